// Round 1
// baseline (2814.802 us; speedup 1.0000x reference)
//
#include <hip/hip_runtime.h>

// ---------------------------------------------------------------------------
// 4-layer GCN: z = GCN4(relu(GCN3(GCN2(relu(GCN1(x))))))
// GCN layer: out[d] = isd[d] * sum_{e: dst=d} isd[src_e] * h[src_e]
//                     + h[d] * isd[d]^2 + b        (h = x @ W)
// ---------------------------------------------------------------------------

static __global__ void hist_kernel(const int* __restrict__ dst, int* __restrict__ counts, int E) {
  int i = blockIdx.x * blockDim.x + threadIdx.x;
  if (i < E) atomicAdd(&counts[dst[i]], 1);
}

static __global__ void isd_kernel(const int* __restrict__ counts, float* __restrict__ isd, int n) {
  int i = blockIdx.x * blockDim.x + threadIdx.x;
  if (i < n) isd[i] = rsqrtf((float)counts[i] + 1.0f);
}

// single-block exclusive scan over counts -> row_ptr[0..n], row_ptr[n] = total
static __global__ void scan_kernel(const int* __restrict__ counts, int* __restrict__ row_ptr, int n) {
  __shared__ int sh[1024];
  __shared__ int carry_sh;
  if (threadIdx.x == 0) carry_sh = 0;
  __syncthreads();
  for (int base = 0; base < n; base += 1024) {
    int i = base + (int)threadIdx.x;
    int v = (i < n) ? counts[i] : 0;
    sh[threadIdx.x] = v;
    __syncthreads();
    for (int off = 1; off < 1024; off <<= 1) {
      int t = 0;
      if ((int)threadIdx.x >= off) t = sh[threadIdx.x - off];
      __syncthreads();
      sh[threadIdx.x] += t;
      __syncthreads();
    }
    int incl = sh[threadIdx.x];
    int carry = carry_sh;
    if (i < n) row_ptr[i] = carry + (incl - v);
    __syncthreads();
    if (threadIdx.x == 0) carry_sh = carry + sh[1023];
    __syncthreads();
  }
  if (threadIdx.x == 0) row_ptr[n] = carry_sh;
}

static __global__ void fill_kernel(const int* __restrict__ src, const int* __restrict__ dst,
                                   const int* __restrict__ row_ptr, int* __restrict__ cursor,
                                   int* __restrict__ csr_src, int E) {
  int i = blockIdx.x * blockDim.x + threadIdx.x;
  if (i < E) {
    int d = dst[i];
    int p = row_ptr[d] + atomicAdd(&cursor[d], 1);
    csr_src[p] = src[i];
  }
}

// H[n,NOUT] = X[n,K] @ W[K,NOUT]. 64x64 tile, 256 threads, 4x4 per thread.
// X tile + 64-row W chunk staged in LDS (<= ~50KB total).
template<int K, int NOUT>
__global__ void gemm_kernel(const float* __restrict__ X, const float* __restrict__ W,
                            float* __restrict__ H, int n) {
  constexpr int BM = 64, BN = 64;
  __shared__ float xs[BM][K + 4];
  __shared__ float wsh[64][BN];
  const int tid = threadIdx.x;
  const int bm = blockIdx.x * BM;
  const int bc = blockIdx.y * BN;

  for (int v = tid; v < BM * (K / 4); v += 256) {
    int r = v / (K / 4), c4 = v % (K / 4);
    int gr = bm + r;
    float4 val = make_float4(0.f, 0.f, 0.f, 0.f);
    if (gr < n) val = *(const float4*)&X[(size_t)gr * K + c4 * 4];
    *(float4*)&xs[r][c4 * 4] = val;
  }

  const int ty = tid >> 4, tx = tid & 15;
  const int r0 = ty * 4, c0 = tx * 4;
  float acc[4][4];
#pragma unroll
  for (int i = 0; i < 4; ++i)
#pragma unroll
    for (int j = 0; j < 4; ++j) acc[i][j] = 0.f;

  for (int kb = 0; kb < K; kb += 64) {
    __syncthreads();  // xs ready (first iter) / previous wsh consumed
    for (int v = tid; v < 64 * (BN / 4); v += 256) {
      int r = v / (BN / 4), c4 = v % (BN / 4);
      *(float4*)&wsh[r][c4 * 4] = *(const float4*)&W[(size_t)(kb + r) * NOUT + bc + c4 * 4];
    }
    __syncthreads();
#pragma unroll
    for (int k = 0; k < 64; k += 4) {
      float a[4][4], w[4][4];
#pragma unroll
      for (int i = 0; i < 4; ++i) {
        float4 t = *(const float4*)&xs[r0 + i][kb + k];
        a[i][0] = t.x; a[i][1] = t.y; a[i][2] = t.z; a[i][3] = t.w;
      }
#pragma unroll
      for (int kk = 0; kk < 4; ++kk) {
        float4 t = *(const float4*)&wsh[k + kk][c0];
        w[kk][0] = t.x; w[kk][1] = t.y; w[kk][2] = t.z; w[kk][3] = t.w;
      }
#pragma unroll
      for (int i = 0; i < 4; ++i)
#pragma unroll
        for (int j = 0; j < 4; ++j)
          acc[i][j] += a[i][0] * w[0][j] + a[i][1] * w[1][j]
                     + a[i][2] * w[2][j] + a[i][3] * w[3][j];
    }
  }

#pragma unroll
  for (int i = 0; i < 4; ++i) {
    int gr = bm + r0 + i;
    if (gr < n) {
      float4 o = make_float4(acc[i][0], acc[i][1], acc[i][2], acc[i][3]);
      *(float4*)&H[(size_t)gr * NOUT + bc + c0] = o;
    }
  }
}

// One wave per dst node; lane-parallel over D (float2/lane for D=128).
template<int D, bool RELU>
__global__ void agg_kernel(const float* __restrict__ h, const int* __restrict__ row_ptr,
                           const int* __restrict__ csr_src, const float* __restrict__ isd,
                           const float* __restrict__ bias, float* __restrict__ out, int n) {
  int gw = (int)((blockIdx.x * (size_t)blockDim.x + threadIdx.x) >> 6);
  int lane = threadIdx.x & 63;
  if (gw >= n) return;
  constexpr int V = D / 64;
  int beg = row_ptr[gw], end = row_ptr[gw + 1];
  float acc[V];
#pragma unroll
  for (int j = 0; j < V; ++j) acc[j] = 0.f;

  int e = beg;
  int s_next = (e < end) ? csr_src[e] : 0;
  while (e < end) {
    int s = s_next;
    ++e;
    if (e < end) s_next = csr_src[e];  // prefetch next src while row load in flight
    float w = isd[s];
    if (V == 2) {
      float2 v = *(const float2*)(h + (size_t)s * D + lane * 2);
      acc[0] += w * v.x;
      acc[1] += w * v.y;
    } else {
      acc[0] += w * h[(size_t)s * D + lane];
    }
  }

  float wd = isd[gw];
  float sl = wd * wd;  // 1/deg
  if (V == 2) {
    float2 hv = *(const float2*)(h + (size_t)gw * D + lane * 2);
    float2 bv = *(const float2*)(bias + lane * 2);
    float o0 = wd * acc[0] + sl * hv.x + bv.x;
    float o1 = wd * acc[1] + sl * hv.y + bv.y;
    if (RELU) { o0 = fmaxf(o0, 0.f); o1 = fmaxf(o1, 0.f); }
    *(float2*)(out + (size_t)gw * D + lane * 2) = make_float2(o0, o1);
  } else {
    float hv = h[(size_t)gw * D + lane];
    float bv = bias[lane];
    float o0 = wd * acc[0] + sl * hv + bv;
    if (RELU) o0 = fmaxf(o0, 0.f);
    out[(size_t)gw * D + lane] = o0;
  }
}

static inline size_t align_up(size_t x, size_t a) { return (x + a - 1) & ~(a - 1); }

extern "C" void kernel_launch(void* const* d_in, const int* in_sizes, int n_in,
                              void* d_out, int out_size, void* d_ws, size_t ws_size,
                              hipStream_t stream) {
  const float* X  = (const float*)d_in[0];
  const float* W1 = (const float*)d_in[1];
  const float* b1 = (const float*)d_in[2];
  const float* W2 = (const float*)d_in[3];
  const float* b2 = (const float*)d_in[4];
  const float* W3 = (const float*)d_in[5];
  const float* b3 = (const float*)d_in[6];
  const float* W4 = (const float*)d_in[7];
  const float* b4 = (const float*)d_in[8];
  const int*   ei = (const int*)d_in[9];

  const int N = in_sizes[0] / 128;
  const int E = in_sizes[9] / 2;
  const int* src = ei;
  const int* dst = ei + E;
  float* OUT = (float*)d_out;

  char* ws = (char*)d_ws;
  size_t off = 0;
  auto alloc = [&](size_t bytes) { void* p = ws + off; off = align_up(off + bytes, 256); return p; };
  int*   counts  = (int*)alloc((size_t)N * 4);
  int*   cursor  = (int*)alloc((size_t)N * 4);
  int*   row_ptr = (int*)alloc(((size_t)N + 1) * 4);
  float* isd     = (float*)alloc((size_t)N * 4);
  int*   csr_src = (int*)alloc((size_t)E * 4);
  float* A       = (float*)alloc((size_t)N * 128 * 4);
  float* A_lo = A;                      // N x 64 view
  float* A_hi = A + (size_t)N * 64;     // N x 64 view

  hipMemsetAsync(counts, 0, (size_t)N * 4, stream);
  hipMemsetAsync(cursor, 0, (size_t)N * 4, stream);

  int eb = (E + 255) / 256;
  int nb = (N + 255) / 256;
  hist_kernel<<<eb, 256, 0, stream>>>(dst, counts, E);
  isd_kernel<<<nb, 256, 0, stream>>>(counts, isd, N);
  scan_kernel<<<1, 1024, 0, stream>>>(counts, row_ptr, N);
  fill_kernel<<<eb, 256, 0, stream>>>(src, dst, row_ptr, cursor, csr_src, E);

  const int gm = (N + 63) / 64;
  const int ab = (int)(((size_t)N * 64 + 255) / 256);

  // L1: h1 = X @ W1 -> A ; z1 = agg(relu) -> OUT
  gemm_kernel<128, 128><<<dim3(gm, 2), 256, 0, stream>>>(X, W1, A, N);
  agg_kernel<128, true><<<ab, 256, 0, stream>>>(A, row_ptr, csr_src, isd, b1, OUT, N);
  // L2: h2 = z1 @ W2 -> A_lo ; z2 = agg -> A_hi
  gemm_kernel<128, 64><<<dim3(gm, 1), 256, 0, stream>>>(OUT, W2, A_lo, N);
  agg_kernel<64, false><<<ab, 256, 0, stream>>>(A_lo, row_ptr, csr_src, isd, b2, A_hi, N);
  // L3: h3 = z2 @ W3 -> OUT ; z3 = agg(relu) -> A
  gemm_kernel<64, 128><<<dim3(gm, 2), 256, 0, stream>>>(A_hi, W3, OUT, N);
  agg_kernel<128, true><<<ab, 256, 0, stream>>>(OUT, row_ptr, csr_src, isd, b3, A, N);
  // L4: h4 = z3 @ W4 -> OUT ; z4 = agg -> A ; copy A -> OUT
  gemm_kernel<128, 128><<<dim3(gm, 2), 256, 0, stream>>>(A, W4, OUT, N);
  agg_kernel<128, false><<<ab, 256, 0, stream>>>(OUT, row_ptr, csr_src, isd, b4, A, N);
  hipMemcpyAsync(OUT, A, (size_t)N * 128 * 4, hipMemcpyDeviceToDevice, stream);
}

// Round 2
// 1717.566 us; speedup vs baseline: 1.6388x; 1.6388x over previous
//
#include <hip/hip_runtime.h>

// ---------------------------------------------------------------------------
// 4-layer GCN: z = GCN4(relu(GCN3(GCN2(relu(GCN1(x))))))
// GCN layer: out[d] = isd[d] * sum_{e: dst=d} isd[src_e] * h[src_e]
//                     + h[d] * isd[d]^2 + b        (h = x @ W)
// ---------------------------------------------------------------------------

static __global__ void hist_kernel(const int* __restrict__ dst, int* __restrict__ counts, int E) {
  int i = blockIdx.x * blockDim.x + threadIdx.x;
  if (i < E) atomicAdd(&counts[dst[i]], 1);
}

static __global__ void isd_kernel(const int* __restrict__ counts, float* __restrict__ isd, int n) {
  int i = blockIdx.x * blockDim.x + threadIdx.x;
  if (i < n) isd[i] = rsqrtf((float)counts[i] + 1.0f);
}

// single-block exclusive scan over counts -> row_ptr[0..n], row_ptr[n] = total
static __global__ void scan_kernel(const int* __restrict__ counts, int* __restrict__ row_ptr, int n) {
  __shared__ int sh[1024];
  __shared__ int carry_sh;
  if (threadIdx.x == 0) carry_sh = 0;
  __syncthreads();
  for (int base = 0; base < n; base += 1024) {
    int i = base + (int)threadIdx.x;
    int v = (i < n) ? counts[i] : 0;
    sh[threadIdx.x] = v;
    __syncthreads();
    for (int off = 1; off < 1024; off <<= 1) {
      int t = 0;
      if ((int)threadIdx.x >= off) t = sh[threadIdx.x - off];
      __syncthreads();
      sh[threadIdx.x] += t;
      __syncthreads();
    }
    int incl = sh[threadIdx.x];
    int carry = carry_sh;
    if (i < n) row_ptr[i] = carry + (incl - v);
    __syncthreads();
    if (threadIdx.x == 0) carry_sh = carry + sh[1023];
    __syncthreads();
  }
  if (threadIdx.x == 0) row_ptr[n] = carry_sh;
}

static __global__ void fill_kernel(const int* __restrict__ src, const int* __restrict__ dst,
                                   const int* __restrict__ row_ptr, int* __restrict__ cursor,
                                   int* __restrict__ csr_src, int E) {
  int i = blockIdx.x * blockDim.x + threadIdx.x;
  if (i < E) {
    int d = dst[i];
    int p = row_ptr[d] + atomicAdd(&cursor[d], 1);
    csr_src[p] = src[i];
  }
}

// H[n,NOUT] = X[n,K] @ W[K,NOUT]. 64x64 tile, 256 threads, 4x4 per thread.
template<int K, int NOUT>
__device__ __forceinline__ void gemm_body(const float* __restrict__ X, const float* __restrict__ W,
                                          float* __restrict__ H, int n) {
  constexpr int BM = 64, BN = 64;
  __shared__ float xs[BM][K + 4];
  __shared__ float wsh[64][BN];
  const int tid = threadIdx.x;
  const int bm = blockIdx.x * BM;
  const int bc = blockIdx.y * BN;

  for (int v = tid; v < BM * (K / 4); v += 256) {
    int r = v / (K / 4), c4 = v % (K / 4);
    int gr = bm + r;
    float4 val = make_float4(0.f, 0.f, 0.f, 0.f);
    if (gr < n) val = *(const float4*)&X[(size_t)gr * K + c4 * 4];
    *(float4*)&xs[r][c4 * 4] = val;
  }

  const int ty = tid >> 4, tx = tid & 15;
  const int r0 = ty * 4, c0 = tx * 4;
  float acc[4][4];
#pragma unroll
  for (int i = 0; i < 4; ++i)
#pragma unroll
    for (int j = 0; j < 4; ++j) acc[i][j] = 0.f;

#pragma unroll 1
  for (int kb = 0; kb < K; kb += 64) {
    __syncthreads();  // xs ready (first iter) / previous wsh consumed
    for (int v = tid; v < 64 * (BN / 4); v += 256) {
      int r = v / (BN / 4), c4 = v % (BN / 4);
      *(float4*)&wsh[r][c4 * 4] = *(const float4*)&W[(size_t)(kb + r) * NOUT + bc + c4 * 4];
    }
    __syncthreads();
#pragma unroll
    for (int k = 0; k < 64; k += 4) {
      float4 w0 = *(const float4*)&wsh[k + 0][c0];
      float4 w1 = *(const float4*)&wsh[k + 1][c0];
      float4 w2 = *(const float4*)&wsh[k + 2][c0];
      float4 w3 = *(const float4*)&wsh[k + 3][c0];
#pragma unroll
      for (int i = 0; i < 4; ++i) {
        float4 av = *(const float4*)&xs[r0 + i][kb + k];
        acc[i][0] += av.x * w0.x + av.y * w1.x + av.z * w2.x + av.w * w3.x;
        acc[i][1] += av.x * w0.y + av.y * w1.y + av.z * w2.y + av.w * w3.y;
        acc[i][2] += av.x * w0.z + av.y * w1.z + av.z * w2.z + av.w * w3.z;
        acc[i][3] += av.x * w0.w + av.y * w1.w + av.z * w2.w + av.w * w3.w;
      }
    }
  }

#pragma unroll
  for (int i = 0; i < 4; ++i) {
    int gr = bm + r0 + i;
    if (gr < n) {
      float4 o = make_float4(acc[i][0], acc[i][1], acc[i][2], acc[i][3]);
      *(float4*)&H[(size_t)gr * NOUT + bc + c0] = o;
    }
  }
}

#define DEF_GEMM(NAME, K, NOUT)                                                          \
  __global__ __launch_bounds__(256, 2) void NAME(const float* __restrict__ X,            \
                                                 const float* __restrict__ W,            \
                                                 float* __restrict__ H, int n) {         \
    gemm_body<K, NOUT>(X, W, H, n);                                                      \
  }
DEF_GEMM(gemm1_k128_n128, 128, 128)
DEF_GEMM(gemm2_k128_n64, 128, 64)
DEF_GEMM(gemm3_k64_n128, 64, 128)
DEF_GEMM(gemm4_k128_n128, 128, 128)

// One wave per dst node; lane-parallel over D (float2/lane for D=128).
template<int D, bool RELU>
__device__ __forceinline__ void agg_body(const float* __restrict__ h, const int* __restrict__ row_ptr,
                                         const int* __restrict__ csr_src, const float* __restrict__ isd,
                                         const float* __restrict__ bias, float* __restrict__ out, int n) {
  int gw = (int)((blockIdx.x * (size_t)blockDim.x + threadIdx.x) >> 6);
  int lane = threadIdx.x & 63;
  if (gw >= n) return;
  constexpr int V = D / 64;
  int beg = row_ptr[gw], end = row_ptr[gw + 1];
  float acc[V];
#pragma unroll
  for (int j = 0; j < V; ++j) acc[j] = 0.f;

  int e = beg;
  int s_next = (e < end) ? csr_src[e] : 0;
  while (e < end) {
    int s = s_next;
    ++e;
    if (e < end) s_next = csr_src[e];  // prefetch next src index
    float w = isd[s];
    if (V == 2) {
      float2 v = *(const float2*)(h + (size_t)s * D + lane * 2);
      acc[0] += w * v.x;
      acc[1] += w * v.y;
    } else {
      acc[0] += w * h[(size_t)s * D + lane];
    }
  }

  float wd = isd[gw];
  float sl = wd * wd;  // 1/deg
  if (V == 2) {
    float2 hv = *(const float2*)(h + (size_t)gw * D + lane * 2);
    float2 bv = *(const float2*)(bias + lane * 2);
    float o0 = wd * acc[0] + sl * hv.x + bv.x;
    float o1 = wd * acc[1] + sl * hv.y + bv.y;
    if (RELU) { o0 = fmaxf(o0, 0.f); o1 = fmaxf(o1, 0.f); }
    *(float2*)(out + (size_t)gw * D + lane * 2) = make_float2(o0, o1);
  } else {
    float hv = h[(size_t)gw * D + lane];
    float bv = bias[lane];
    float o0 = wd * acc[0] + sl * hv + bv;
    if (RELU) o0 = fmaxf(o0, 0.f);
    out[(size_t)gw * D + lane] = o0;
  }
}

#define DEF_AGG(NAME, D, RELU)                                                             \
  __global__ void NAME(const float* __restrict__ h, const int* __restrict__ row_ptr,       \
                       const int* __restrict__ csr_src, const float* __restrict__ isd,     \
                       const float* __restrict__ bias, float* __restrict__ out, int n) {   \
    agg_body<D, RELU>(h, row_ptr, csr_src, isd, bias, out, n);                             \
  }
DEF_AGG(agg1_relu_d128, 128, true)
DEF_AGG(agg2_d64, 64, false)
DEF_AGG(agg3_relu_d128, 128, true)
DEF_AGG(agg4_d128, 128, false)

static inline size_t align_up(size_t x, size_t a) { return (x + a - 1) & ~(a - 1); }

extern "C" void kernel_launch(void* const* d_in, const int* in_sizes, int n_in,
                              void* d_out, int out_size, void* d_ws, size_t ws_size,
                              hipStream_t stream) {
  const float* X  = (const float*)d_in[0];
  const float* W1 = (const float*)d_in[1];
  const float* b1 = (const float*)d_in[2];
  const float* W2 = (const float*)d_in[3];
  const float* b2 = (const float*)d_in[4];
  const float* W3 = (const float*)d_in[5];
  const float* b3 = (const float*)d_in[6];
  const float* W4 = (const float*)d_in[7];
  const float* b4 = (const float*)d_in[8];
  const int*   ei = (const int*)d_in[9];

  const int N = in_sizes[0] / 128;
  const int E = in_sizes[9] / 2;
  const int* src = ei;
  const int* dst = ei + E;
  float* OUT = (float*)d_out;

  char* ws = (char*)d_ws;
  size_t off = 0;
  auto alloc = [&](size_t bytes) { void* p = ws + off; off = align_up(off + bytes, 256); return p; };
  int*   counts  = (int*)alloc((size_t)N * 4);
  int*   cursor  = (int*)alloc((size_t)N * 4);
  int*   row_ptr = (int*)alloc(((size_t)N + 1) * 4);
  float* isd     = (float*)alloc((size_t)N * 4);
  int*   csr_src = (int*)alloc((size_t)E * 4);
  float* A       = (float*)alloc((size_t)N * 128 * 4);
  float* A_lo = A;                      // N x 64 view
  float* A_hi = A + (size_t)N * 64;     // N x 64 view

  hipMemsetAsync(counts, 0, (size_t)N * 4, stream);
  hipMemsetAsync(cursor, 0, (size_t)N * 4, stream);

  int eb = (E + 255) / 256;
  int nb = (N + 255) / 256;
  hist_kernel<<<eb, 256, 0, stream>>>(dst, counts, E);
  isd_kernel<<<nb, 256, 0, stream>>>(counts, isd, N);
  scan_kernel<<<1, 1024, 0, stream>>>(counts, row_ptr, N);
  fill_kernel<<<eb, 256, 0, stream>>>(src, dst, row_ptr, cursor, csr_src, E);

  const int gm = (N + 63) / 64;
  const int ab = (int)(((size_t)N * 64 + 255) / 256);

  // L1: h1 = X @ W1 -> A ; z1 = agg(relu) -> OUT
  gemm1_k128_n128<<<dim3(gm, 2), 256, 0, stream>>>(X, W1, A, N);
  agg1_relu_d128<<<ab, 256, 0, stream>>>(A, row_ptr, csr_src, isd, b1, OUT, N);
  // L2: h2 = z1 @ W2 -> A_lo ; z2 = agg -> A_hi
  gemm2_k128_n64<<<dim3(gm, 1), 256, 0, stream>>>(OUT, W2, A_lo, N);
  agg2_d64<<<ab, 256, 0, stream>>>(A_lo, row_ptr, csr_src, isd, b2, A_hi, N);
  // L3: h3 = z2 @ W3 -> OUT ; z3 = agg(relu) -> A
  gemm3_k64_n128<<<dim3(gm, 2), 256, 0, stream>>>(A_hi, W3, OUT, N);
  agg3_relu_d128<<<ab, 256, 0, stream>>>(OUT, row_ptr, csr_src, isd, b3, A, N);
  // L4: h4 = z3 @ W4 -> OUT ; z4 = agg -> A ; copy A -> OUT
  gemm4_k128_n128<<<dim3(gm, 2), 256, 0, stream>>>(A, W4, OUT, N);
  agg4_d128<<<ab, 256, 0, stream>>>(OUT, row_ptr, csr_src, isd, b4, A, N);
  hipMemcpyAsync(OUT, A, (size_t)N * 128 * 4, hipMemcpyDeviceToDevice, stream);
}

// Round 3
// 857.461 us; speedup vs baseline: 3.2827x; 2.0031x over previous
//
#include <hip/hip_runtime.h>

// ---------------------------------------------------------------------------
// 4-layer GCN: z = GCN4(relu(GCN3(GCN2(relu(GCN1(x))))))
// GCN layer: out[d] = isd[d] * sum_{e: dst=d} isd[src_e] * h[src_e]
//                     + h[d] * isd[d]^2 + b        (h = x @ W)
// ---------------------------------------------------------------------------

static __global__ void hist_kernel(const int* __restrict__ dst, int* __restrict__ counts, int E) {
  int i = blockIdx.x * blockDim.x + threadIdx.x;
  if (i < E) atomicAdd(&counts[dst[i]], 1);
}

static __global__ void isd_kernel(const int* __restrict__ counts, float* __restrict__ isd, int n) {
  int i = blockIdx.x * blockDim.x + threadIdx.x;
  if (i < n) isd[i] = rsqrtf((float)counts[i] + 1.0f);
}

// 3-pass exclusive scan: pass1 per-block scan + block sums, pass2 scan sums,
// pass3 add offsets. n=100k -> 391 blocks (fits single-block pass2).
static __global__ void scan1_kernel(const int* __restrict__ counts, int* __restrict__ row_ptr,
                                    int* __restrict__ blksum, int n) {
  __shared__ int sh[256];
  int i = blockIdx.x * 256 + threadIdx.x;
  int v = (i < n) ? counts[i] : 0;
  sh[threadIdx.x] = v;
  __syncthreads();
  for (int off = 1; off < 256; off <<= 1) {
    int t = ((int)threadIdx.x >= off) ? sh[threadIdx.x - off] : 0;
    __syncthreads();
    sh[threadIdx.x] += t;
    __syncthreads();
  }
  if (i < n) row_ptr[i] = sh[threadIdx.x] - v;  // exclusive, pre-offset
  if (threadIdx.x == 255) blksum[blockIdx.x] = sh[255];
}

static __global__ void scan2_kernel(const int* __restrict__ blksum, int* __restrict__ blkoff,
                                    int* __restrict__ row_ptr, int nb, int n) {
  __shared__ int sh[1024];
  int v = ((int)threadIdx.x < nb) ? blksum[threadIdx.x] : 0;
  sh[threadIdx.x] = v;
  __syncthreads();
  for (int off = 1; off < 1024; off <<= 1) {
    int t = ((int)threadIdx.x >= off) ? sh[threadIdx.x - off] : 0;
    __syncthreads();
    sh[threadIdx.x] += t;
    __syncthreads();
  }
  if ((int)threadIdx.x < nb) blkoff[threadIdx.x] = sh[threadIdx.x] - v;
  if ((int)threadIdx.x == nb - 1) row_ptr[n] = sh[threadIdx.x];  // total E
}

static __global__ void scan3_kernel(int* __restrict__ row_ptr, const int* __restrict__ blkoff, int n) {
  int i = blockIdx.x * 256 + threadIdx.x;
  if (i < n) row_ptr[i] += blkoff[blockIdx.x];
}

static __global__ void fill_kernel(const int* __restrict__ src, const int* __restrict__ dst,
                                   const int* __restrict__ row_ptr, int* __restrict__ cursor,
                                   int* __restrict__ csr_src, int E) {
  int i = blockIdx.x * blockDim.x + threadIdx.x;
  if (i < E) {
    int d = dst[i];
    int p = row_ptr[d] + atomicAdd(&cursor[d], 1);
    csr_src[p] = src[i];
  }
}

// H[n,NOUT] = X[n,K] @ W[K,NOUT]. 64x64 tile, 256 threads, 4x4 per thread.
// Inner k-loop is ROLLED (#pragma unroll 1): full unroll let the scheduler
// hoist ~300 LDS-read results -> VGPR spill -> 2.3 GB scratch traffic (r2).
template<int K, int NOUT>
__device__ __forceinline__ void gemm_body(const float* __restrict__ X, const float* __restrict__ W,
                                          float* __restrict__ H, int n) {
  constexpr int BM = 64, BN = 64;
  __shared__ float xs[BM][K + 4];
  __shared__ float wsh[64][BN];
  const int tid = threadIdx.x;
  const int bm = blockIdx.x * BM;
  const int bc = blockIdx.y * BN;

  for (int v = tid; v < BM * (K / 4); v += 256) {
    int r = v / (K / 4), c4 = v % (K / 4);
    int gr = bm + r;
    float4 val = make_float4(0.f, 0.f, 0.f, 0.f);
    if (gr < n) val = *(const float4*)&X[(size_t)gr * K + c4 * 4];
    *(float4*)&xs[r][c4 * 4] = val;
  }

  const int ty = tid >> 4, tx = tid & 15;
  const int r0 = ty * 4, c0 = tx * 4;
  float acc[4][4];
#pragma unroll
  for (int i = 0; i < 4; ++i)
#pragma unroll
    for (int j = 0; j < 4; ++j) acc[i][j] = 0.f;

#pragma unroll 1
  for (int kb = 0; kb < K; kb += 64) {
    __syncthreads();  // xs ready (first iter) / previous wsh consumed
    for (int v = tid; v < 64 * (BN / 4); v += 256) {
      int r = v / (BN / 4), c4 = v % (BN / 4);
      *(float4*)&wsh[r][c4 * 4] = *(const float4*)&W[(size_t)(kb + r) * NOUT + bc + c4 * 4];
    }
    __syncthreads();
#pragma unroll 1
    for (int k = 0; k < 64; k += 4) {
      float4 w0 = *(const float4*)&wsh[k + 0][c0];
      float4 w1 = *(const float4*)&wsh[k + 1][c0];
      float4 w2 = *(const float4*)&wsh[k + 2][c0];
      float4 w3 = *(const float4*)&wsh[k + 3][c0];
#pragma unroll
      for (int i = 0; i < 4; ++i) {
        float4 av = *(const float4*)&xs[r0 + i][kb + k];
        acc[i][0] += av.x * w0.x + av.y * w1.x + av.z * w2.x + av.w * w3.x;
        acc[i][1] += av.x * w0.y + av.y * w1.y + av.z * w2.y + av.w * w3.y;
        acc[i][2] += av.x * w0.z + av.y * w1.z + av.z * w2.z + av.w * w3.z;
        acc[i][3] += av.x * w0.w + av.y * w1.w + av.z * w2.w + av.w * w3.w;
      }
    }
  }

#pragma unroll
  for (int i = 0; i < 4; ++i) {
    int gr = bm + r0 + i;
    if (gr < n) {
      float4 o = make_float4(acc[i][0], acc[i][1], acc[i][2], acc[i][3]);
      *(float4*)&H[(size_t)gr * NOUT + bc + c0] = o;
    }
  }
}

#define DEF_GEMM(NAME, K, NOUT)                                                          \
  __global__ __launch_bounds__(256, 2) void NAME(const float* __restrict__ X,            \
                                                 const float* __restrict__ W,            \
                                                 float* __restrict__ H, int n) {         \
    gemm_body<K, NOUT>(X, W, H, n);                                                      \
  }
DEF_GEMM(gemm1_k128_n128, 128, 128)
DEF_GEMM(gemm2_k128_n64, 128, 64)
DEF_GEMM(gemm3_k64_n128, 64, 128)
DEF_GEMM(gemm4_k128_n128, 128, 128)

// One wave per dst node; lane-parallel over D (float2/lane for D=128).
template<int D, bool RELU>
__device__ __forceinline__ void agg_body(const float* __restrict__ h, const int* __restrict__ row_ptr,
                                         const int* __restrict__ csr_src, const float* __restrict__ isd,
                                         const float* __restrict__ bias, float* __restrict__ out, int n) {
  int gw = (int)((blockIdx.x * (size_t)blockDim.x + threadIdx.x) >> 6);
  int lane = threadIdx.x & 63;
  if (gw >= n) return;
  constexpr int V = D / 64;
  int beg = row_ptr[gw], end = row_ptr[gw + 1];
  float acc[V];
#pragma unroll
  for (int j = 0; j < V; ++j) acc[j] = 0.f;

  int e = beg;
  int s_next = (e < end) ? csr_src[e] : 0;
  while (e < end) {
    int s = s_next;
    ++e;
    if (e < end) s_next = csr_src[e];  // prefetch next src index
    float w = isd[s];
    if (V == 2) {
      float2 v = *(const float2*)(h + (size_t)s * D + lane * 2);
      acc[0] += w * v.x;
      acc[1] += w * v.y;
    } else {
      acc[0] += w * h[(size_t)s * D + lane];
    }
  }

  float wd = isd[gw];
  float sl = wd * wd;  // 1/deg
  if (V == 2) {
    float2 hv = *(const float2*)(h + (size_t)gw * D + lane * 2);
    float2 bv = *(const float2*)(bias + lane * 2);
    float o0 = wd * acc[0] + sl * hv.x + bv.x;
    float o1 = wd * acc[1] + sl * hv.y + bv.y;
    if (RELU) { o0 = fmaxf(o0, 0.f); o1 = fmaxf(o1, 0.f); }
    *(float2*)(out + (size_t)gw * D + lane * 2) = make_float2(o0, o1);
  } else {
    float hv = h[(size_t)gw * D + lane];
    float bv = bias[lane];
    float o0 = wd * acc[0] + sl * hv + bv;
    if (RELU) o0 = fmaxf(o0, 0.f);
    out[(size_t)gw * D + lane] = o0;
  }
}

#define DEF_AGG(NAME, D, RELU)                                                             \
  __global__ void NAME(const float* __restrict__ h, const int* __restrict__ row_ptr,       \
                       const int* __restrict__ csr_src, const float* __restrict__ isd,     \
                       const float* __restrict__ bias, float* __restrict__ out, int n) {   \
    agg_body<D, RELU>(h, row_ptr, csr_src, isd, bias, out, n);                             \
  }
DEF_AGG(agg1_relu_d128, 128, true)
DEF_AGG(agg2_d64, 64, false)
DEF_AGG(agg3_relu_d128, 128, true)
DEF_AGG(agg4_d128, 128, false)

static inline size_t align_up(size_t x, size_t a) { return (x + a - 1) & ~(a - 1); }

extern "C" void kernel_launch(void* const* d_in, const int* in_sizes, int n_in,
                              void* d_out, int out_size, void* d_ws, size_t ws_size,
                              hipStream_t stream) {
  const float* X  = (const float*)d_in[0];
  const float* W1 = (const float*)d_in[1];
  const float* b1 = (const float*)d_in[2];
  const float* W2 = (const float*)d_in[3];
  const float* b2 = (const float*)d_in[4];
  const float* W3 = (const float*)d_in[5];
  const float* b3 = (const float*)d_in[6];
  const float* W4 = (const float*)d_in[7];
  const float* b4 = (const float*)d_in[8];
  const int*   ei = (const int*)d_in[9];

  const int N = in_sizes[0] / 128;
  const int E = in_sizes[9] / 2;
  const int* src = ei;
  const int* dst = ei + E;
  float* OUT = (float*)d_out;

  char* ws = (char*)d_ws;
  size_t off = 0;
  auto alloc = [&](size_t bytes) { void* p = ws + off; off = align_up(off + bytes, 256); return p; };
  int*   counts  = (int*)alloc((size_t)N * 4);
  int*   cursor  = (int*)alloc((size_t)N * 4);
  int*   row_ptr = (int*)alloc(((size_t)N + 1) * 4);
  float* isd     = (float*)alloc((size_t)N * 4);
  int*   csr_src = (int*)alloc((size_t)E * 4);
  int*   blksum  = (int*)alloc(1024 * 4);
  int*   blkoff  = (int*)alloc(1024 * 4);
  float* A       = (float*)alloc((size_t)N * 128 * 4);
  float* A_lo = A;                      // N x 64 view
  float* A_hi = A + (size_t)N * 64;     // N x 64 view

  hipMemsetAsync(counts, 0, (size_t)N * 4, stream);
  hipMemsetAsync(cursor, 0, (size_t)N * 4, stream);

  int eb = (E + 255) / 256;
  int nb = (N + 255) / 256;   // 391 for N=100k, must be <= 1024 for scan2
  hist_kernel<<<eb, 256, 0, stream>>>(dst, counts, E);
  isd_kernel<<<nb, 256, 0, stream>>>(counts, isd, N);
  scan1_kernel<<<nb, 256, 0, stream>>>(counts, row_ptr, blksum, N);
  scan2_kernel<<<1, 1024, 0, stream>>>(blksum, blkoff, row_ptr, nb, N);
  scan3_kernel<<<nb, 256, 0, stream>>>(row_ptr, blkoff, N);
  fill_kernel<<<eb, 256, 0, stream>>>(src, dst, row_ptr, cursor, csr_src, E);

  const int gm = (N + 63) / 64;
  const int ab = (int)(((size_t)N * 64 + 255) / 256);

  // L1: h1 = X @ W1 -> A ; z1 = agg(relu) -> OUT
  gemm1_k128_n128<<<dim3(gm, 2), 256, 0, stream>>>(X, W1, A, N);
  agg1_relu_d128<<<ab, 256, 0, stream>>>(A, row_ptr, csr_src, isd, b1, OUT, N);
  // L2: h2 = z1 @ W2 -> A_lo ; z2 = agg -> A_hi
  gemm2_k128_n64<<<dim3(gm, 1), 256, 0, stream>>>(OUT, W2, A_lo, N);
  agg2_d64<<<ab, 256, 0, stream>>>(A_lo, row_ptr, csr_src, isd, b2, A_hi, N);
  // L3: h3 = z2 @ W3 -> OUT ; z3 = agg(relu) -> A
  gemm3_k64_n128<<<dim3(gm, 2), 256, 0, stream>>>(A_hi, W3, OUT, N);
  agg3_relu_d128<<<ab, 256, 0, stream>>>(OUT, row_ptr, csr_src, isd, b3, A, N);
  // L4: h4 = z3 @ W4 -> OUT ; z4 = agg -> A ; copy A -> OUT
  gemm4_k128_n128<<<dim3(gm, 2), 256, 0, stream>>>(A, W4, OUT, N);
  agg4_d128<<<ab, 256, 0, stream>>>(OUT, row_ptr, csr_src, isd, b4, A, N);
  hipMemcpyAsync(OUT, A, (size_t)N * 128 * 4, hipMemcpyDeviceToDevice, stream);
}

// Round 4
// 741.206 us; speedup vs baseline: 3.7976x; 1.1568x over previous
//
#include <hip/hip_runtime.h>

// ---------------------------------------------------------------------------
// 4-layer GCN, restructured:
//   P(Y)_d = isd_d * (sum_{e:dst=d} Ys_src + Ys_d)  with Ys = isd*Y (pre-scaled)
//   gcn(Z,W,b) = P(Z@W) + b = P(Z)@W + b   (commute to aggregate in smaller dim)
// L1: Ys1 = isd*(X@W1); z1 = relu(P' + b1)            [agg on 128]
// L2: Ys2 = isd*(z1@W2); zs2 = isd*(P' + b2)          [agg on 64, post-scaled]
// L3: g2 = P(z2) from zs2 [agg on 64]; z3 = relu(g2@W3 + b3)
// L4: Ys4 = isd*(z3@W4); out = P' + b4 -> d_out       [agg on 128]
// ---------------------------------------------------------------------------

static __global__ void hist_kernel(const int* __restrict__ dst, int* __restrict__ counts, int E) {
  int i = blockIdx.x * blockDim.x + threadIdx.x;
  if (i < E) atomicAdd(&counts[dst[i]], 1);
}

static __global__ void isd_kernel(const int* __restrict__ counts, float* __restrict__ isd, int n) {
  int i = blockIdx.x * blockDim.x + threadIdx.x;
  if (i < n) isd[i] = rsqrtf((float)counts[i] + 1.0f);
}

// 3-pass exclusive scan
static __global__ void scan1_kernel(const int* __restrict__ counts, int* __restrict__ row_ptr,
                                    int* __restrict__ blksum, int n) {
  __shared__ int sh[256];
  int i = blockIdx.x * 256 + threadIdx.x;
  int v = (i < n) ? counts[i] : 0;
  sh[threadIdx.x] = v;
  __syncthreads();
  for (int off = 1; off < 256; off <<= 1) {
    int t = ((int)threadIdx.x >= off) ? sh[threadIdx.x - off] : 0;
    __syncthreads();
    sh[threadIdx.x] += t;
    __syncthreads();
  }
  if (i < n) row_ptr[i] = sh[threadIdx.x] - v;
  if (threadIdx.x == 255) blksum[blockIdx.x] = sh[255];
}

static __global__ void scan2_kernel(const int* __restrict__ blksum, int* __restrict__ blkoff,
                                    int* __restrict__ row_ptr, int nb, int n) {
  __shared__ int sh[1024];
  int v = ((int)threadIdx.x < nb) ? blksum[threadIdx.x] : 0;
  sh[threadIdx.x] = v;
  __syncthreads();
  for (int off = 1; off < 1024; off <<= 1) {
    int t = ((int)threadIdx.x >= off) ? sh[threadIdx.x - off] : 0;
    __syncthreads();
    sh[threadIdx.x] += t;
    __syncthreads();
  }
  if ((int)threadIdx.x < nb) blkoff[threadIdx.x] = sh[threadIdx.x] - v;
  if ((int)threadIdx.x == nb - 1) row_ptr[n] = sh[threadIdx.x];
}

static __global__ void scan3_kernel(int* __restrict__ row_ptr, const int* __restrict__ blkoff, int n) {
  int i = blockIdx.x * 256 + threadIdx.x;
  if (i < n) row_ptr[i] += blkoff[blockIdx.x];
}

static __global__ void fill_kernel(const int* __restrict__ src, const int* __restrict__ dst,
                                   const int* __restrict__ row_ptr, int* __restrict__ cursor,
                                   int* __restrict__ csr_src, int E) {
  int i = blockIdx.x * blockDim.x + threadIdx.x;
  if (i < E) {
    int d = dst[i];
    int p = row_ptr[d] + atomicAdd(&cursor[d], 1);
    csr_src[p] = src[i];
  }
}

// ---------------------------------------------------------------------------
// GEMM: H[n,NOUT] = epi(X[n,K] @ W[K,NOUT]). 64x64 tile, 256 thr, 4x4/thread.
// Rolled k-loop (full unroll caused VGPR spill -> GB of scratch, r2).
// EPI 0: H = isd[row] * acc     EPI 1: H = relu(acc + bias[col])
// ---------------------------------------------------------------------------
template<int K, int NOUT, int EPI>
__device__ __forceinline__ void gemm_body(const float* __restrict__ X, const float* __restrict__ W,
                                          const float* __restrict__ aux, float* __restrict__ H, int n) {
  constexpr int BM = 64, BN = 64;
  __shared__ float xs[BM][K + 4];
  __shared__ float wsh[64][BN];
  const int tid = threadIdx.x;
  const int bm = blockIdx.x * BM;
  const int bc = blockIdx.y * BN;

  for (int v = tid; v < BM * (K / 4); v += 256) {
    int r = v / (K / 4), c4 = v % (K / 4);
    int gr = bm + r;
    float4 val = make_float4(0.f, 0.f, 0.f, 0.f);
    if (gr < n) val = *(const float4*)&X[(size_t)gr * K + c4 * 4];
    *(float4*)&xs[r][c4 * 4] = val;
  }

  const int ty = tid >> 4, tx = tid & 15;
  const int r0 = ty * 4, c0 = tx * 4;
  float acc[4][4];
#pragma unroll
  for (int i = 0; i < 4; ++i)
#pragma unroll
    for (int j = 0; j < 4; ++j) acc[i][j] = 0.f;

#pragma unroll 1
  for (int kb = 0; kb < K; kb += 64) {
    __syncthreads();
    for (int v = tid; v < 64 * (BN / 4); v += 256) {
      int r = v / (BN / 4), c4 = v % (BN / 4);
      *(float4*)&wsh[r][c4 * 4] = *(const float4*)&W[(size_t)(kb + r) * NOUT + bc + c4 * 4];
    }
    __syncthreads();
#pragma unroll 1
    for (int k = 0; k < 64; k += 4) {
      float4 w0 = *(const float4*)&wsh[k + 0][c0];
      float4 w1 = *(const float4*)&wsh[k + 1][c0];
      float4 w2 = *(const float4*)&wsh[k + 2][c0];
      float4 w3 = *(const float4*)&wsh[k + 3][c0];
#pragma unroll
      for (int i = 0; i < 4; ++i) {
        float4 av = *(const float4*)&xs[r0 + i][kb + k];
        acc[i][0] += av.x * w0.x + av.y * w1.x + av.z * w2.x + av.w * w3.x;
        acc[i][1] += av.x * w0.y + av.y * w1.y + av.z * w2.y + av.w * w3.y;
        acc[i][2] += av.x * w0.z + av.y * w1.z + av.z * w2.z + av.w * w3.z;
        acc[i][3] += av.x * w0.w + av.y * w1.w + av.z * w2.w + av.w * w3.w;
      }
    }
  }

  float4 bv = make_float4(0.f, 0.f, 0.f, 0.f);
  if (EPI == 1) bv = *(const float4*)&aux[bc + c0];
#pragma unroll
  for (int i = 0; i < 4; ++i) {
    int gr = bm + r0 + i;
    if (gr < n) {
      float4 o;
      if (EPI == 0) {
        float s = aux[gr];
        o = make_float4(acc[i][0] * s, acc[i][1] * s, acc[i][2] * s, acc[i][3] * s);
      } else {
        o = make_float4(fmaxf(acc[i][0] + bv.x, 0.f), fmaxf(acc[i][1] + bv.y, 0.f),
                        fmaxf(acc[i][2] + bv.z, 0.f), fmaxf(acc[i][3] + bv.w, 0.f));
      }
      *(float4*)&H[(size_t)gr * NOUT + bc + c0] = o;
    }
  }
}

#define DEF_GEMM(NAME, K, NOUT, EPI)                                                     \
  __global__ __launch_bounds__(256, 2) void NAME(const float* __restrict__ X,            \
                                                 const float* __restrict__ W,            \
                                                 const float* __restrict__ aux,          \
                                                 float* __restrict__ H, int n) {         \
    gemm_body<K, NOUT, EPI>(X, W, aux, H, n);                                            \
  }
DEF_GEMM(gemm1_k128_n128_scale, 128, 128, 0)
DEF_GEMM(gemm2_k128_n64_scale, 128, 64, 0)
DEF_GEMM(gemm3_k64_n128_biasrelu, 64, 128, 1)
DEF_GEMM(gemm4_k128_n128_scale, 128, 128, 0)

// ---------------------------------------------------------------------------
// Aggregation over pre-scaled rows hs: acc_d = sum hs[src] ; then
//   t = isd_d * (acc + hs_d); [+bias]; [relu]; [*isd_d]  -> out
// One wave per dst; 4-edge unroll for memory-level parallelism.
// ---------------------------------------------------------------------------
template<int D, bool RELU, bool HASBIAS, bool POSTSCALE>
__device__ __forceinline__ void agg_body(const float* __restrict__ hs, const int* __restrict__ row_ptr,
                                         const int* __restrict__ csr_src, const float* __restrict__ isd,
                                         const float* __restrict__ bias, float* __restrict__ out, int n) {
  int gw = (int)((blockIdx.x * (size_t)blockDim.x + threadIdx.x) >> 6);
  int lane = threadIdx.x & 63;
  if (gw >= n) return;
  constexpr int V = D / 64;
  int beg = row_ptr[gw], end = row_ptr[gw + 1];
  float acc0 = 0.f, acc1 = 0.f;

  int e = beg;
  for (; e + 4 <= end; e += 4) {
    int s0 = csr_src[e + 0];
    int s1 = csr_src[e + 1];
    int s2 = csr_src[e + 2];
    int s3 = csr_src[e + 3];
    if (V == 2) {
      float2 v0 = *(const float2*)(hs + (size_t)s0 * D + lane * 2);
      float2 v1 = *(const float2*)(hs + (size_t)s1 * D + lane * 2);
      float2 v2 = *(const float2*)(hs + (size_t)s2 * D + lane * 2);
      float2 v3 = *(const float2*)(hs + (size_t)s3 * D + lane * 2);
      acc0 += (v0.x + v1.x) + (v2.x + v3.x);
      acc1 += (v0.y + v1.y) + (v2.y + v3.y);
    } else {
      float v0 = hs[(size_t)s0 * D + lane];
      float v1 = hs[(size_t)s1 * D + lane];
      float v2 = hs[(size_t)s2 * D + lane];
      float v3 = hs[(size_t)s3 * D + lane];
      acc0 += (v0 + v1) + (v2 + v3);
    }
  }
  for (; e < end; ++e) {
    int s = csr_src[e];
    if (V == 2) {
      float2 v = *(const float2*)(hs + (size_t)s * D + lane * 2);
      acc0 += v.x;
      acc1 += v.y;
    } else {
      acc0 += hs[(size_t)s * D + lane];
    }
  }

  float wd = isd[gw];
  if (V == 2) {
    float2 hv = *(const float2*)(hs + (size_t)gw * D + lane * 2);
    float o0 = wd * (acc0 + hv.x);
    float o1 = wd * (acc1 + hv.y);
    if (HASBIAS) {
      float2 bv = *(const float2*)(bias + lane * 2);
      o0 += bv.x; o1 += bv.y;
    }
    if (RELU) { o0 = fmaxf(o0, 0.f); o1 = fmaxf(o1, 0.f); }
    if (POSTSCALE) { o0 *= wd; o1 *= wd; }
    *(float2*)(out + (size_t)gw * D + lane * 2) = make_float2(o0, o1);
  } else {
    float hv = hs[(size_t)gw * D + lane];
    float o0 = wd * (acc0 + hv);
    if (HASBIAS) o0 += bias[lane];
    if (RELU) o0 = fmaxf(o0, 0.f);
    if (POSTSCALE) o0 *= wd;
    out[(size_t)gw * D + lane] = o0;
  }
}

#define DEF_AGG(NAME, D, RELU, HASBIAS, POSTSCALE)                                         \
  __global__ void NAME(const float* __restrict__ hs, const int* __restrict__ row_ptr,      \
                       const int* __restrict__ csr_src, const float* __restrict__ isd,     \
                       const float* __restrict__ bias, float* __restrict__ out, int n) {   \
    agg_body<D, RELU, HASBIAS, POSTSCALE>(hs, row_ptr, csr_src, isd, bias, out, n);        \
  }
DEF_AGG(agg1_d128_biasrelu, 128, true, true, false)
DEF_AGG(agg2_d64_bias_postscale, 64, false, true, true)
DEF_AGG(agg3_d64_plain, 64, false, false, false)
DEF_AGG(agg4_d128_bias, 128, false, true, false)

static inline size_t align_up(size_t x, size_t a) { return (x + a - 1) & ~(a - 1); }

extern "C" void kernel_launch(void* const* d_in, const int* in_sizes, int n_in,
                              void* d_out, int out_size, void* d_ws, size_t ws_size,
                              hipStream_t stream) {
  const float* X  = (const float*)d_in[0];
  const float* W1 = (const float*)d_in[1];
  const float* b1 = (const float*)d_in[2];
  const float* W2 = (const float*)d_in[3];
  const float* b2 = (const float*)d_in[4];
  const float* W3 = (const float*)d_in[5];
  const float* b3 = (const float*)d_in[6];
  const float* W4 = (const float*)d_in[7];
  const float* b4 = (const float*)d_in[8];
  const int*   ei = (const int*)d_in[9];

  const int N = in_sizes[0] / 128;
  const int E = in_sizes[9] / 2;
  const int* src = ei;
  const int* dst = ei + E;
  float* OUT = (float*)d_out;

  char* ws = (char*)d_ws;
  size_t off = 0;
  auto alloc = [&](size_t bytes) { void* p = ws + off; off = align_up(off + bytes, 256); return p; };
  int*   counts  = (int*)alloc((size_t)N * 4);
  int*   cursor  = (int*)alloc((size_t)N * 4);
  int*   row_ptr = (int*)alloc(((size_t)N + 1) * 4);
  float* isd     = (float*)alloc((size_t)N * 4);
  int*   csr_src = (int*)alloc((size_t)E * 4);
  int*   blksum  = (int*)alloc(1024 * 4);
  int*   blkoff  = (int*)alloc(1024 * 4);
  float* A       = (float*)alloc((size_t)N * 128 * 4);
  float* A_lo = A;                   // N x 64 view
  float* A_hi = A + (size_t)N * 64;  // N x 64 view

  hipMemsetAsync(counts, 0, (size_t)N * 4, stream);
  hipMemsetAsync(cursor, 0, (size_t)N * 4, stream);

  int eb = (E + 255) / 256;
  int nb = (N + 255) / 256;  // 391 for N=100k, must be <= 1024 for scan2
  hist_kernel<<<eb, 256, 0, stream>>>(dst, counts, E);
  isd_kernel<<<nb, 256, 0, stream>>>(counts, isd, N);
  scan1_kernel<<<nb, 256, 0, stream>>>(counts, row_ptr, blksum, N);
  scan2_kernel<<<1, 1024, 0, stream>>>(blksum, blkoff, row_ptr, nb, N);
  scan3_kernel<<<nb, 256, 0, stream>>>(row_ptr, blkoff, N);
  fill_kernel<<<eb, 256, 0, stream>>>(src, dst, row_ptr, cursor, csr_src, E);

  const int gm = (N + 63) / 64;
  const int ab = (int)(((size_t)N * 64 + 255) / 256);

  // L1: Ys1 = isd*(X@W1) -> A ; z1 = relu(P'+b1) -> OUT
  gemm1_k128_n128_scale<<<dim3(gm, 2), 256, 0, stream>>>(X, W1, isd, A, N);
  agg1_d128_biasrelu<<<ab, 256, 0, stream>>>(A, row_ptr, csr_src, isd, b1, OUT, N);
  // L2: Ys2 = isd*(z1@W2) -> A_lo ; zs2 = isd*(P'+b2) -> A_hi
  gemm2_k128_n64_scale<<<dim3(gm, 1), 256, 0, stream>>>(OUT, W2, isd, A_lo, N);
  agg2_d64_bias_postscale<<<ab, 256, 0, stream>>>(A_lo, row_ptr, csr_src, isd, b2, A_hi, N);
  // L3 (commuted): g2 = P(z2) from zs2 -> A_lo ; z3 = relu(g2@W3+b3) -> OUT
  agg3_d64_plain<<<ab, 256, 0, stream>>>(A_hi, row_ptr, csr_src, isd, nullptr, A_lo, N);
  gemm3_k64_n128_biasrelu<<<dim3(gm, 2), 256, 0, stream>>>(A_lo, W3, b3, OUT, N);
  // L4: Ys4 = isd*(z3@W4) -> A ; out = P'+b4 -> OUT (final)
  gemm4_k128_n128_scale<<<dim3(gm, 2), 256, 0, stream>>>(OUT, W4, isd, A, N);
  agg4_d128_bias<<<ab, 256, 0, stream>>>(A, row_ptr, csr_src, isd, b4, OUT, N);
}